// Round 9
// baseline (33.912 us; speedup 1.0000x reference)
//
#include <hip/hip_runtime.h>
#include <hip/hip_bf16.h>

// HSTU positional encoder, fused. 2 rows per wave, 8 rows per 256-thread block.
// A/B vs R5: stores are REGULAR (L2-allocating, like the 6.9 TB/s fill kernel);
// emb loads stay non-temporal (protect L2 for the ts/pos gather hot set).

typedef float f32x4 __attribute__((ext_vector_type(4)));

__global__ __launch_bounds__(256) void hstu_pos_enc_kernel(
    const f32x4* __restrict__ emb4,        // [L, D4]
    const f32x4* __restrict__ posw4,       // [P, D4]
    const f32x4* __restrict__ tsw4,        // [NTB+1, D4]
    const int*   __restrict__ seq_offsets, // [B+1]
    const int*   __restrict__ seq_lengths, // [B]
    const int*   __restrict__ num_targets, // [B]
    const int*   __restrict__ seq_ts,      // [L]
    f32x4* __restrict__ out4,              // [L, D4]
    int L, int D4, int B, int P, int NTB, float alpha)
{
    const int wv   = threadIdx.x >> 6;
    const int lane = threadIdx.x & 63;
    const int row0 = blockIdx.x * 8 + wv * 2;   // 2 rows per wave
    if (row0 >= L) return;
    const int  row1 = row0 + 1;
    const bool has1 = row1 < L;

    // ---- tiny loads, issued up front in parallel ----
    const int off_l = seq_offsets[min(lane, B)];       // lane l holds offsets[l]
    const int len_l = seq_lengths[min(lane, B - 1)];
    const int tgt_l = num_targets[min(lane, B - 1)];
    const int tt0i  = seq_ts[row0];
    const int tt1i  = seq_ts[has1 ? row1 : row0];

    // ---- branchless batch search (B <= 63 here) ----
    int b0, b1;
    if (B <= 63) {
        const bool in = (lane >= 1) && (lane <= B);
        b0 = __popcll(__ballot(in && (row0 >= off_l)));
        b1 = __popcll(__ballot(in && (row1 >= off_l)));
    } else {
        b0 = 0; while (b0 + 1 < B && seq_offsets[b0 + 1] <= row0) ++b0;
        b1 = b0; while (b1 + 1 < B && seq_offsets[b1 + 1] <= row1) ++b1;
    }

    const int off_b0  = __shfl(off_l, min(b0, 63));
    const int off_b1  = __shfl(off_l, min(b1, 63));
    const int off_b0e = __shfl(off_l, min(b0 + 1, 63));
    const int off_b1e = __shfl(off_l, min(b1 + 1, 63));
    const int len0 = __shfl(len_l, min(b0, 63));
    const int len1 = __shfl(len_l, min(b1, 63));
    const int tgt0 = __shfl(tgt_l, min(b0, 63));
    const int tgt1 = __shfl(tgt_l, min(b1, 63));

    const int qt0i = seq_ts[off_b0e - 1];
    const int qt1i = seq_ts[off_b1e - 1];

    // ---- per-row index math ----
    auto mkpos = [&](int row, int off_b, int len, int tgt) {
        int high = max(len, 0) - max(tgt, 0);
        high = max(high, 0);
        int rel = row - off_b;
        int pi = (rel < high) ? rel : high;      // MCSL==0: rel>=0 branch dead
        pi = high - pi;
        return max(min(pi, P - 1), 0);
    };
    auto mkts = [&](int qti, int tti) {
        float dtv = fmaxf((float)qti - (float)tti, 1e-6f) * (1.0f / 60.0f);
        int ti = (int)sqrtf(dtv);
        return max(min(ti, NTB), 0);
    };
    const int pi0 = mkpos(row0, off_b0, len0, tgt0);
    const int pi1 = mkpos(row1, off_b1, len1, tgt1);
    const int ti0 = mkts(qt0i, tt0i);
    const int ti1 = mkts(qt1i, tt1i);

    const long e0b = (long)row0 * D4, e1b = (long)row1 * D4;
    const long p0b = (long)pi0  * D4, p1b = (long)pi1  * D4;
    const long t0b = (long)ti0  * D4, t1b = (long)ti1  * D4;

    if (D4 == 128) {
        const f32x4 e00 = __builtin_nontemporal_load(&emb4[e0b + lane]);
        const f32x4 e01 = __builtin_nontemporal_load(&emb4[e0b + lane + 64]);
        const f32x4 p00 = posw4[p0b + lane];
        const f32x4 p01 = posw4[p0b + lane + 64];
        const f32x4 t00 = tsw4[t0b + lane];
        const f32x4 t01 = tsw4[t0b + lane + 64];
        f32x4 e10, e11, p10, p11, t10, t11;
        if (has1) {
            e10 = __builtin_nontemporal_load(&emb4[e1b + lane]);
            e11 = __builtin_nontemporal_load(&emb4[e1b + lane + 64]);
            p10 = posw4[p1b + lane];
            p11 = posw4[p1b + lane + 64];
            t10 = tsw4[t1b + lane];
            t11 = tsw4[t1b + lane + 64];
        }
        f32x4 o00 = e00 * alpha + (p00 + t00);
        f32x4 o01 = e01 * alpha + (p01 + t01);
        out4[e0b + lane]      = o00;
        out4[e0b + lane + 64] = o01;
        if (has1) {
            f32x4 o10 = e10 * alpha + (p10 + t10);
            f32x4 o11 = e11 * alpha + (p11 + t11);
            out4[e1b + lane]      = o10;
            out4[e1b + lane + 64] = o11;
        }
    } else {
        for (int s = lane; s < D4; s += 64) {
            const f32x4 e = __builtin_nontemporal_load(&emb4[e0b + s]);
            out4[e0b + s] = e * alpha + (posw4[p0b + s] + tsw4[t0b + s]);
        }
        if (has1) for (int s = lane; s < D4; s += 64) {
            const f32x4 e = __builtin_nontemporal_load(&emb4[e1b + s]);
            out4[e1b + s] = e * alpha + (posw4[p1b + s] + tsw4[t1b + s]);
        }
    }
}

extern "C" void kernel_launch(void* const* d_in, const int* in_sizes, int n_in,
                              void* d_out, int out_size, void* d_ws, size_t ws_size,
                              hipStream_t stream) {
    // inputs: 0 max_seq_len, 1 seq_lengths[B], 2 seq_offsets[B+1],
    // 3 seq_embeddings[L*D], 4 num_targets[B], 5 seq_timestamps[L],
    // 6 pos_weight[P*D], 7 ts_weight[(NTB+1)*D]
    const int*   seq_lengths = (const int*)d_in[1];
    const int*   seq_offsets = (const int*)d_in[2];
    const float* emb         = (const float*)d_in[3];
    const int*   num_targets = (const int*)d_in[4];
    const int*   seq_ts      = (const int*)d_in[5];
    const float* posw        = (const float*)d_in[6];
    const float* tsw         = (const float*)d_in[7];

    const int B   = in_sizes[1];
    const int L   = in_sizes[5];
    const int D   = in_sizes[3] / L;
    const int D4  = D / 4;
    const int P   = in_sizes[6] / D;
    const int NTB = in_sizes[7] / D - 1;
    const float alpha = sqrtf((float)D);

    const int rows_per_block = 8;                 // 4 waves x 2 rows
    const int grid = (L + rows_per_block - 1) / rows_per_block;

    hstu_pos_enc_kernel<<<grid, 256, 0, stream>>>(
        (const f32x4*)emb, (const f32x4*)posw, (const f32x4*)tsw,
        seq_offsets, seq_lengths, num_targets, seq_ts,
        (f32x4*)d_out, L, D4, B, P, NTB, alpha);
}

// Round 10
// 33.178 us; speedup vs baseline: 1.0221x; 1.0221x over previous
//
#include <hip/hip_runtime.h>
#include <hip/hip_bf16.h>

// HSTU positional encoder, fused. 4 rows per wave (16 per 256-thread block).
// All 24 big loads (emb/pos/ts x 4 rows x 2 slots) issue before any math ->
// ~24 KiB HBM in flight per wave. Per-lane qt table hoisted (lane b holds the
// query timestamp of batch b) so the per-row chain is ballot->shfl->fp->gather.
// nt on emb loads + out stores (best from R4/R9 A/B).

typedef float f32x4 __attribute__((ext_vector_type(4)));

__global__ __launch_bounds__(256) void hstu_pos_enc_kernel(
    const f32x4* __restrict__ emb4,        // [L, D4]
    const f32x4* __restrict__ posw4,       // [P, D4]
    const f32x4* __restrict__ tsw4,        // [NTB+1, D4]
    const int*   __restrict__ seq_offsets, // [B+1]
    const int*   __restrict__ seq_lengths, // [B]
    const int*   __restrict__ num_targets, // [B]
    const int*   __restrict__ seq_ts,      // [L]
    f32x4* __restrict__ out4,              // [L, D4]
    int L, int D4, int B, int P, int NTB, float alpha)
{
    const int wv   = threadIdx.x >> 6;
    const int lane = threadIdx.x & 63;
    const int row0 = blockIdx.x * 16 + wv * 4;   // 4 rows per wave
    if (row0 >= L) return;

    // ---- per-lane batch tables: lane l holds entry l ----
    const int off_l = seq_offsets[min(lane, B)];
    const int len_l = seq_lengths[min(lane, B - 1)];
    const int tgt_l = num_targets[min(lane, B - 1)];
    // lane b holds query time of batch b = seq_ts[offsets[b+1]-1]
    const int qtidx = seq_offsets[min(lane + 1, B)] - 1;
    const int qt_l  = seq_ts[max(qtidx, 0)];
    const bool inr  = (lane >= 1) && (lane <= B);   // B <= 63 fast path

    int   rows[4];
    int   pi[4], ti[4];
    bool  has[4];

    #pragma unroll
    for (int r = 0; r < 4; ++r) {
        rows[r] = row0 + r;
        has[r]  = rows[r] < L;
    }
    const int rB = has[3] ? 3 : (has[2] ? 2 : (has[1] ? 1 : 0));

    // token timestamps (parallel tiny loads)
    int tts[4];
    #pragma unroll
    for (int r = 0; r < 4; ++r) tts[r] = seq_ts[has[r] ? rows[r] : row0];

    #pragma unroll
    for (int r = 0; r < 4; ++r) {
        const int row = has[r] ? rows[r] : row0;
        int b;
        if (B <= 63) {
            b = __popcll(__ballot(inr && (row >= off_l)));
        } else {
            b = 0; while (b + 1 < B && seq_offsets[b + 1] <= row) ++b;
        }
        const int off_b = __shfl(off_l, min(b, 63));
        const int len   = __shfl(len_l, min(b, 63));
        const int tgt   = __shfl(tgt_l, min(b, 63));
        const int qti   = __shfl(qt_l,  min(b, 63));

        int high = max(len, 0) - max(tgt, 0);
        high = max(high, 0);
        int rel = row - off_b;
        int p = (rel < high) ? rel : high;        // MCSL==0: rel>=0 branch dead
        p = high - p;
        pi[r] = max(min(p, P - 1), 0);

        float dtv = fmaxf((float)qti - (float)tts[r], 1e-6f) * (1.0f / 60.0f);
        int t = (int)sqrtf(dtv);
        ti[r] = max(min(t, NTB), 0);
    }

    if (D4 == 128) {
        // issue ALL big loads before any math
        f32x4 e[4][2], p[4][2], t[4][2];
        #pragma unroll
        for (int r = 0; r < 4; ++r) {
            const int rr = has[r] ? r : rB;
            const long eb = (long)rows[rr] * D4;
            e[r][0] = __builtin_nontemporal_load(&emb4[eb + lane]);
            e[r][1] = __builtin_nontemporal_load(&emb4[eb + lane + 64]);
        }
        #pragma unroll
        for (int r = 0; r < 4; ++r) {
            const int rr = has[r] ? r : rB;
            const long pb = (long)pi[rr] * D4;
            p[r][0] = posw4[pb + lane];
            p[r][1] = posw4[pb + lane + 64];
        }
        #pragma unroll
        for (int r = 0; r < 4; ++r) {
            const int rr = has[r] ? r : rB;
            const long tb = (long)ti[rr] * D4;
            t[r][0] = tsw4[tb + lane];
            t[r][1] = tsw4[tb + lane + 64];
        }
        #pragma unroll
        for (int r = 0; r < 4; ++r) {
            if (!has[r]) continue;
            const long eb = (long)rows[r] * D4;
            f32x4 o0 = e[r][0] * alpha + (p[r][0] + t[r][0]);
            f32x4 o1 = e[r][1] * alpha + (p[r][1] + t[r][1]);
            __builtin_nontemporal_store(o0, &out4[eb + lane]);
            __builtin_nontemporal_store(o1, &out4[eb + lane + 64]);
        }
    } else {
        for (int r = 0; r < 4; ++r) {
            if (!has[r]) continue;
            const long eb = (long)rows[r] * D4;
            const long pb = (long)pi[r]  * D4;
            const long tb = (long)ti[r]  * D4;
            for (int s = lane; s < D4; s += 64) {
                const f32x4 ev = __builtin_nontemporal_load(&emb4[eb + s]);
                f32x4 o = ev * alpha + (posw4[pb + s] + tsw4[tb + s]);
                __builtin_nontemporal_store(o, &out4[eb + s]);
            }
        }
    }
}

extern "C" void kernel_launch(void* const* d_in, const int* in_sizes, int n_in,
                              void* d_out, int out_size, void* d_ws, size_t ws_size,
                              hipStream_t stream) {
    // inputs: 0 max_seq_len, 1 seq_lengths[B], 2 seq_offsets[B+1],
    // 3 seq_embeddings[L*D], 4 num_targets[B], 5 seq_timestamps[L],
    // 6 pos_weight[P*D], 7 ts_weight[(NTB+1)*D]
    const int*   seq_lengths = (const int*)d_in[1];
    const int*   seq_offsets = (const int*)d_in[2];
    const float* emb         = (const float*)d_in[3];
    const int*   num_targets = (const int*)d_in[4];
    const int*   seq_ts      = (const int*)d_in[5];
    const float* posw        = (const float*)d_in[6];
    const float* tsw         = (const float*)d_in[7];

    const int B   = in_sizes[1];
    const int L   = in_sizes[5];
    const int D   = in_sizes[3] / L;
    const int D4  = D / 4;
    const int P   = in_sizes[6] / D;
    const int NTB = in_sizes[7] / D - 1;
    const float alpha = sqrtf((float)D);

    const int rows_per_block = 16;                // 4 waves x 4 rows
    const int grid = (L + rows_per_block - 1) / rows_per_block;

    hstu_pos_enc_kernel<<<grid, 256, 0, stream>>>(
        (const f32x4*)emb, (const f32x4*)posw, (const f32x4*)tsw,
        seq_offsets, seq_lengths, num_targets, seq_ts,
        (f32x4*)d_out, L, D4, B, P, NTB, alpha);
}

// Round 11
// 30.991 us; speedup vs baseline: 1.0942x; 1.0706x over previous
//
#include <hip/hip_runtime.h>
#include <hip/hip_bf16.h>

// FINAL: HSTU positional encoder, fused. 2 rows per wave, 8 rows per block.
// Best configuration found (R5, 31.0us):
//  - non-temporal emb loads + out stores (the zero-reuse streams bypass L2,
//    protecting it for the pos/ts gather hot set): +10% vs regular. [R4/R9 A/B]
//  - pos/ts gathers cacheable (L2/L3-served; FETCH_SIZE confirmed compulsory).
//  - ballot/popc batch search + per-lane table loads (no dependent-load chain).
// Ablated neutral-or-negative: index-split kernel, XCD swizzle, persistent
// grid, regular stores, 4 rows/wave. ~8.6 TB/s aggregate 4-stream traffic.

typedef float f32x4 __attribute__((ext_vector_type(4)));

__global__ __launch_bounds__(256) void hstu_pos_enc_kernel(
    const f32x4* __restrict__ emb4,        // [L, D4]
    const f32x4* __restrict__ posw4,       // [P, D4]
    const f32x4* __restrict__ tsw4,        // [NTB+1, D4]
    const int*   __restrict__ seq_offsets, // [B+1]
    const int*   __restrict__ seq_lengths, // [B]
    const int*   __restrict__ num_targets, // [B]
    const int*   __restrict__ seq_ts,      // [L]
    f32x4* __restrict__ out4,              // [L, D4]
    int L, int D4, int B, int P, int NTB, float alpha)
{
    const int wv   = threadIdx.x >> 6;
    const int lane = threadIdx.x & 63;
    const int row0 = blockIdx.x * 8 + wv * 2;   // 2 rows per wave
    if (row0 >= L) return;
    const int  row1 = row0 + 1;
    const bool has1 = row1 < L;

    // ---- tiny loads, issued up front in parallel ----
    const int off_l = seq_offsets[min(lane, B)];       // lane l holds offsets[l]
    const int len_l = seq_lengths[min(lane, B - 1)];
    const int tgt_l = num_targets[min(lane, B - 1)];
    const int tt0i  = seq_ts[row0];
    const int tt1i  = seq_ts[has1 ? row1 : row0];

    // ---- branchless batch search (B <= 63 here) ----
    int b0, b1;
    if (B <= 63) {
        const bool in = (lane >= 1) && (lane <= B);
        b0 = __popcll(__ballot(in && (row0 >= off_l)));
        b1 = __popcll(__ballot(in && (row1 >= off_l)));
    } else {
        b0 = 0; while (b0 + 1 < B && seq_offsets[b0 + 1] <= row0) ++b0;
        b1 = b0; while (b1 + 1 < B && seq_offsets[b1 + 1] <= row1) ++b1;
    }

    const int off_b0  = __shfl(off_l, min(b0, 63));
    const int off_b1  = __shfl(off_l, min(b1, 63));
    const int off_b0e = __shfl(off_l, min(b0 + 1, 63));
    const int off_b1e = __shfl(off_l, min(b1 + 1, 63));
    const int len0 = __shfl(len_l, min(b0, 63));
    const int len1 = __shfl(len_l, min(b1, 63));
    const int tgt0 = __shfl(tgt_l, min(b0, 63));
    const int tgt1 = __shfl(tgt_l, min(b1, 63));

    const int qt0i = seq_ts[off_b0e - 1];
    const int qt1i = seq_ts[off_b1e - 1];

    // ---- per-row index math ----
    auto mkpos = [&](int row, int off_b, int len, int tgt) {
        int high = max(len, 0) - max(tgt, 0);
        high = max(high, 0);
        int rel = row - off_b;
        int pi = (rel < high) ? rel : high;      // MCSL==0: rel>=0 branch dead
        pi = high - pi;
        return max(min(pi, P - 1), 0);
    };
    auto mkts = [&](int qti, int tti) {
        float dtv = fmaxf((float)qti - (float)tti, 1e-6f) * (1.0f / 60.0f);
        int ti = (int)sqrtf(dtv);
        return max(min(ti, NTB), 0);
    };
    const int pi0 = mkpos(row0, off_b0, len0, tgt0);
    const int pi1 = mkpos(row1, off_b1, len1, tgt1);
    const int ti0 = mkts(qt0i, tt0i);
    const int ti1 = mkts(qt1i, tt1i);

    const long e0b = (long)row0 * D4, e1b = (long)row1 * D4;
    const long p0b = (long)pi0  * D4, p1b = (long)pi1  * D4;
    const long t0b = (long)ti0  * D4, t1b = (long)ti1  * D4;

    if (D4 == 128) {
        const f32x4 e00 = __builtin_nontemporal_load(&emb4[e0b + lane]);
        const f32x4 e01 = __builtin_nontemporal_load(&emb4[e0b + lane + 64]);
        const f32x4 p00 = posw4[p0b + lane];
        const f32x4 p01 = posw4[p0b + lane + 64];
        const f32x4 t00 = tsw4[t0b + lane];
        const f32x4 t01 = tsw4[t0b + lane + 64];
        f32x4 e10, e11, p10, p11, t10, t11;
        if (has1) {
            e10 = __builtin_nontemporal_load(&emb4[e1b + lane]);
            e11 = __builtin_nontemporal_load(&emb4[e1b + lane + 64]);
            p10 = posw4[p1b + lane];
            p11 = posw4[p1b + lane + 64];
            t10 = tsw4[t1b + lane];
            t11 = tsw4[t1b + lane + 64];
        }
        f32x4 o00 = e00 * alpha + (p00 + t00);
        f32x4 o01 = e01 * alpha + (p01 + t01);
        __builtin_nontemporal_store(o00, &out4[e0b + lane]);
        __builtin_nontemporal_store(o01, &out4[e0b + lane + 64]);
        if (has1) {
            f32x4 o10 = e10 * alpha + (p10 + t10);
            f32x4 o11 = e11 * alpha + (p11 + t11);
            __builtin_nontemporal_store(o10, &out4[e1b + lane]);
            __builtin_nontemporal_store(o11, &out4[e1b + lane + 64]);
        }
    } else {
        for (int s = lane; s < D4; s += 64) {
            const f32x4 e = __builtin_nontemporal_load(&emb4[e0b + s]);
            f32x4 o = e * alpha + (posw4[p0b + s] + tsw4[t0b + s]);
            __builtin_nontemporal_store(o, &out4[e0b + s]);
        }
        if (has1) for (int s = lane; s < D4; s += 64) {
            const f32x4 e = __builtin_nontemporal_load(&emb4[e1b + s]);
            f32x4 o = e * alpha + (posw4[p1b + s] + tsw4[t1b + s]);
            __builtin_nontemporal_store(o, &out4[e1b + s]);
        }
    }
}

extern "C" void kernel_launch(void* const* d_in, const int* in_sizes, int n_in,
                              void* d_out, int out_size, void* d_ws, size_t ws_size,
                              hipStream_t stream) {
    // inputs: 0 max_seq_len, 1 seq_lengths[B], 2 seq_offsets[B+1],
    // 3 seq_embeddings[L*D], 4 num_targets[B], 5 seq_timestamps[L],
    // 6 pos_weight[P*D], 7 ts_weight[(NTB+1)*D]
    const int*   seq_lengths = (const int*)d_in[1];
    const int*   seq_offsets = (const int*)d_in[2];
    const float* emb         = (const float*)d_in[3];
    const int*   num_targets = (const int*)d_in[4];
    const int*   seq_ts      = (const int*)d_in[5];
    const float* posw        = (const float*)d_in[6];
    const float* tsw         = (const float*)d_in[7];

    const int B   = in_sizes[1];
    const int L   = in_sizes[5];
    const int D   = in_sizes[3] / L;
    const int D4  = D / 4;
    const int P   = in_sizes[6] / D;
    const int NTB = in_sizes[7] / D - 1;
    const float alpha = sqrtf((float)D);

    const int rows_per_block = 8;                 // 4 waves x 2 rows
    const int grid = (L + rows_per_block - 1) / rows_per_block;

    hstu_pos_enc_kernel<<<grid, 256, 0, stream>>>(
        (const f32x4*)emb, (const f32x4*)posw, (const f32x4*)tsw,
        seq_offsets, seq_lengths, num_targets, seq_ts,
        (f32x4*)d_out, L, D4, B, P, NTB, alpha);
}